// Round 2
// baseline (227.372 us; speedup 1.0000x reference)
//
#include <hip/hip_runtime.h>
#include <hip/hip_bf16.h>

typedef __attribute__((ext_vector_type(8))) short short8;
typedef __attribute__((ext_vector_type(4))) float floatx4;
typedef __hip_bfloat16 bf16;

#define DIM 768
#define NH 12
#define HD 64
#define BB 16
#define NN 640
#define BH (BB*NH)          // 192
#define MROWS (BB*NN)       // 10240
#define QKVN (3*DIM)        // 2304
#define QSCALE 0.18033688011113205f   // 0.125 * log2(e)
#define LN2SQ 0.4804530139182014f     // ln(2)^2

#define CVT_BLK (MROWS*DIM/4/256)     // 7680
#define TRQ_BLK ((QKVN/32)*(DIM/32))  // 1728
#define TRP_BLK ((DIM/32)*(DIM/32))   // 576

__device__ __forceinline__ floatx4 mfma16(short8 a, short8 b, floatx4 c) {
    return __builtin_amdgcn_mfma_f32_16x16x32_bf16(a, b, c, 0, 0, 0);
}

// async global->LDS, 16B per lane; lds dest = wave-uniform base + lane*16
__device__ __forceinline__ void async_ld16(const bf16* g, bf16* l) {
    __builtin_amdgcn_global_load_lds(
        (const __attribute__((address_space(1))) void*)g,
        (__attribute__((address_space(3))) void*)l, 16, 0, 0);
}

// truncate two f32 to bf16 and pack: lo16 = a, hi16 = b  (one v_perm_b32)
__device__ __forceinline__ unsigned pack_trunc(float a, float b) {
    return __builtin_amdgcn_perm(__float_as_uint(b), __float_as_uint(a), 0x07060302u);
}

// RNE two f32 -> packed bf16x2 (matches __float2bfloat16 numerics)
__device__ __forceinline__ unsigned pack_rne(float a, float b) {
    unsigned sa = (unsigned)__bfloat16_as_ushort(__float2bfloat16(a));
    unsigned sb = (unsigned)__bfloat16_as_ushort(__float2bfloat16(b));
    return sa | (sb << 16);
}

__device__ __forceinline__ float fexp2(float x) {
#if __has_builtin(__builtin_amdgcn_exp2f)
    return __builtin_amdgcn_exp2f(x);
#else
    return exp2f(x);
#endif
}

// ---------------- fused prep: x->bf16 + both weight transposes ----------------
__global__ void prep_all(const float* __restrict__ x,
                         const float* __restrict__ qkv_w,
                         const float* __restrict__ proj_w,
                         bf16* __restrict__ xb,
                         bf16* __restrict__ qwT,
                         bf16* __restrict__ pwT)
{
    __shared__ float tile[32][33];
    const int id = blockIdx.x;
    const int t = threadIdx.x;

    if (id < CVT_BLK) {
        int i = id * 256 + t;
        float4 v = ((const float4*)x)[i];
        *(uint2*)(xb + (size_t)i * 4) =
            make_uint2(pack_rne(v.x, v.y), pack_rne(v.z, v.w));
        return;
    }

    const float* src; bf16* dst; int C, bx, by;
    if (id < CVT_BLK + TRQ_BLK) {
        int j = id - CVT_BLK;
        bx = j % (QKVN/32); by = j / (QKVN/32);
        src = qkv_w; dst = qwT; C = QKVN;
    } else {
        int j = id - CVT_BLK - TRQ_BLK;
        bx = j % (DIM/32); by = j / (DIM/32);
        src = proj_w; dst = pwT; C = DIM;
    }
    const int R = DIM;
    const int tx = t & 31, ty = t >> 5;
    for (int j = 0; j < 4; ++j)
        tile[ty + j*8][tx] = src[(size_t)(by*32 + ty + j*8) * C + bx*32 + tx];
    __syncthreads();
    for (int j = 0; j < 4; ++j)
        dst[(size_t)(bx*32 + ty + j*8) * R + by*32 + tx] = __float2bfloat16(tile[tx][ty + j*8]);
}

// ---------------- QKV GEMM: 256x256 tile, 8-phase counted-vmcnt schedule ----------------
// C = A @ B^T, A [10240][768] bf16, B [2304][768] bf16. 512 thr / 8 waves (2M x 4N),
// per-wave 128x64 output (acc[8][4]). BK=64, 2-deep LDS (128 KiB), half-tile staging:
// each phase = {4-or-12 ds_read_b128 || 2 global_load_lds || bar || lgkm || 16 MFMA || bar},
// vmcnt(6) only at phase-3/7 tails (3 half-tiles stay in flight across barriers).
// Issue/last-read schedule (iter i computes tiles t0=2i buf0 / t1=2i+1 buf1):
//  p0:Ab(t1->b1) p1:Bh0(t2->b0) p2:Bh1(t2) p3:Aa(t2)+vm6 p4:Ab(t2) p5:Bh0(t3->b1)
//  p6:Bh1(t3) p7:Aa(t3)+vm6 ; Ab(t3) lands at next iter's p0. Every overwrite is
// issued >=1 barrier after its region's last read; vm6 forces all data needed by the
// next 4 phases landed chip-wide (barrier follows the wait).
__global__ __launch_bounds__(512, 2) void gemm_qkv256(
    const bf16* __restrict__ A, const bf16* __restrict__ B, const float* __restrict__ bias,
    bf16* __restrict__ outb, bf16* __restrict__ vTo)
{
    constexpr int K = DIM;           // 768, nt = 12 K-tiles, 6 iterations
    constexpr int N = QKVN;          // 2304
    __shared__ __align__(16) bf16 As[2][2][128*64];   // [buf][half][row*64+slot*8]
    __shared__ __align__(16) bf16 Bs[2][2][128*64];

    const int t = threadIdx.x;
    const int lane = t & 63, wave = t >> 6;
    const int l15 = lane & 15, quad = lane >> 4;
    const int wm = wave >> 2;        // A-half this wave consumes (0..1)
    const int wn = wave & 3;         // B quarter (0..3)
    const int hB = wn >> 1;          // B-half this wave consumes
    const int m0 = blockIdx.y * 256, n0 = blockIdx.x * 256;

    floatx4 acc[8][4];
    floatx4 zero = {0.f, 0.f, 0.f, 0.f};
#pragma unroll
    for (int i = 0; i < 8; ++i)
#pragma unroll
        for (int j = 0; j < 4; ++j)
            acc[i][j] = zero;

    // staging map: thread t covers 64 rows/call: row = trow, slot = t&7,
    // source chunk = slot ^ (row&7)  (row&7 == trow&7 for all calls: offsets %8==0)
    const int trow = t >> 3;         // 0..63
    const int gc = ((t & 7) ^ (trow & 7)) << 3;
    const bf16* Ag = A + (size_t)(m0 + trow) * K + gc;
    const bf16* Bg = B + (size_t)(n0 + trow) * K + gc;
    const int tb = t * 8;            // LDS elem offset (wave-uniform base + lane*16)

#define STG_A(buf,h,s,tcol) async_ld16(Ag + (size_t)((h)*128+(s)*64)*K + (tcol), &As[buf][h][(s)*4096 + tb])
#define STG_B(buf,h,s,tcol) async_ld16(Bg + (size_t)((h)*128+(s)*64)*K + (tcol), &Bs[buf][h][(s)*4096 + tb])

    // fragment read offsets (swizzled): row r -> elem r*64 + ((chunk^(r&7))<<3)
    const int swq = (quad ^ (l15 & 7)) << 3;
    const int aoff = l15 * 64 + swq;                       // + fm*1024 ; ^32 = k-half 1
    const int boff = (wn & 1) * 4096 + l15 * 64 + swq;     // + fn*1024

    short8 bfr[4][2];

#define RD_B(buf) do { \
    _Pragma("unroll") \
    for (int fn = 0; fn < 4; ++fn) { \
        const int _ob = boff + fn*1024; \
        bfr[fn][0] = *(const short8*)&Bs[buf][hB][_ob]; \
        bfr[fn][1] = *(const short8*)&Bs[buf][hB][_ob ^ 32]; \
    } } while (0)

#define PHASE(buf, q, RB, STAGES, WAITS) do { \
    const int _o = aoff + (2*(q))*1024; \
    short8 a00 = *(const short8*)&As[buf][wm][_o]; \
    short8 a01 = *(const short8*)&As[buf][wm][_o ^ 32]; \
    short8 a10 = *(const short8*)&As[buf][wm][_o + 1024]; \
    short8 a11 = *(const short8*)&As[buf][wm][(_o + 1024) ^ 32]; \
    RB; \
    STAGES; \
    __builtin_amdgcn_s_barrier(); \
    asm volatile("s_waitcnt lgkmcnt(0)" ::: "memory"); \
    __builtin_amdgcn_sched_barrier(0); \
    __builtin_amdgcn_s_setprio(1); \
    _Pragma("unroll") \
    for (int fn = 0; fn < 4; ++fn) { \
        acc[2*(q)][fn]   = mfma16(bfr[fn][0], a00, acc[2*(q)][fn]); \
        acc[2*(q)+1][fn] = mfma16(bfr[fn][0], a10, acc[2*(q)+1][fn]); \
    } \
    _Pragma("unroll") \
    for (int fn = 0; fn < 4; ++fn) { \
        acc[2*(q)][fn]   = mfma16(bfr[fn][1], a01, acc[2*(q)][fn]); \
        acc[2*(q)+1][fn] = mfma16(bfr[fn][1], a11, acc[2*(q)+1][fn]); \
    } \
    __builtin_amdgcn_s_setprio(0); \
    WAITS; \
    __builtin_amdgcn_s_barrier(); \
} while (0)

    // prologue: T0 (8 calls) + T1's B and A-low (6 calls); vm6 -> T0 landed
    STG_B(0,0,0,0); STG_B(0,0,1,0); STG_B(0,1,0,0); STG_B(0,1,1,0);
    STG_A(0,0,0,0); STG_A(0,1,0,0); STG_A(0,0,1,0); STG_A(0,1,1,0);
    STG_B(1,0,0,64); STG_B(1,0,1,64); STG_B(1,1,0,64); STG_B(1,1,1,64);
    STG_A(1,0,0,64); STG_A(1,1,0,64);
    asm volatile("s_waitcnt vmcnt(6)" ::: "memory");
    __builtin_amdgcn_s_barrier();

    for (int it = 0; it < 6; ++it) {
        const int kb = it * 128;
        const bool more = (it < 5);
        PHASE(0, 0, RD_B(0),
              { STG_A(1,0,1,kb+64); STG_A(1,1,1,kb+64); },
              (void)0);
        PHASE(0, 1, (void)0,
              { if (more) { STG_B(0,0,0,kb+128); STG_B(0,0,1,kb+128); } },
              (void)0);
        PHASE(0, 2, (void)0,
              { if (more) { STG_B(0,1,0,kb+128); STG_B(0,1,1,kb+128); } },
              (void)0);
        PHASE(0, 3, (void)0,
              { if (more) { STG_A(0,0,0,kb+128); STG_A(0,1,0,kb+128); } },
              { if (more) { asm volatile("s_waitcnt vmcnt(6)" ::: "memory"); }
                else      { asm volatile("s_waitcnt vmcnt(0)" ::: "memory"); } });
        PHASE(1, 0, RD_B(1),
              { if (more) { STG_A(0,0,1,kb+128); STG_A(0,1,1,kb+128); } },
              (void)0);
        PHASE(1, 1, (void)0,
              { if (more) { STG_B(1,0,0,kb+192); STG_B(1,0,1,kb+192); } },
              (void)0);
        PHASE(1, 2, (void)0,
              { if (more) { STG_B(1,1,0,kb+192); STG_B(1,1,1,kb+192); } },
              (void)0);
        PHASE(1, 3, (void)0,
              { if (more) { STG_A(1,0,0,kb+192); STG_A(1,1,0,kb+192); } },
              { if (more) { asm volatile("s_waitcnt vmcnt(6)" ::: "memory"); } });
    }
#undef PHASE
#undef RD_B
#undef STG_A
#undef STG_B

    // ---- epilogue: acc[fm][fn][r] = C[m = m0+wm*128+fm*16+l15][n = n0+wn*64+fn*16+quad*4+r]
    const int mb = m0 + wm * 128;
    const int nb = n0 + wn * 64;

    if (n0 >= 2*DIM) {
        // V block: wave's 64-col span = exactly one head; 128-row span never
        // crosses a batch boundary (640 % 128 boundaries align). Per-wave LDS
        // transpose (stride-72 scratch) -> vT[bh][d][tok], coalesced uint4 stores.
        bf16* S = &As[0][0][0] + wave * 2048;      // buffers dead after final barrier
        unsigned short* Su = (unsigned short*)S;
        const int head = (nb - 2*DIM) >> 6;
        const int gm = mb;
        const int bh = (gm / NN) * NH + head;
        const int tokb = gm % NN;
        const int dl = lane >> 2, cc = (lane & 3) * 16;
#pragma unroll
        for (int fmh = 0; fmh < 2; ++fmh) {
#pragma unroll
            for (int fn = 0; fn < 4; ++fn) {
                int nq = nb + fn*16 + quad*4;
                float4 bv = *(const float4*)(bias + nq);
                float bvr[4] = {bv.x, bv.y, bv.z, bv.w};
#pragma unroll
                for (int fi = 0; fi < 4; ++fi) {
#pragma unroll
                    for (int r = 0; r < 4; ++r) {
                        float v = acc[fmh*4 + fi][fn][r] + bvr[r];
                        Su[(quad*4 + r)*72 + fi*16 + l15] =
                            (unsigned short)(__float_as_uint(v) >> 16);
                    }
                }
                // per-wave scratch: in-wave lgkmcnt ordering suffices
                uint4 r0 = *(const uint4*)(S + dl*72 + cc);
                uint4 r1 = *(const uint4*)(S + dl*72 + cc + 8);
                int d = fn*16 + dl;
                bf16* dst = vTo + ((size_t)bh * HD + d) * NN + tokb + fmh*64 + cc;
                *(uint4*)dst = r0;
                *(uint4*)(dst + 8) = r1;
            }
        }
        return;
    }

    const bool isq = (n0 < DIM);
#pragma unroll
    for (int fm = 0; fm < 8; ++fm) {
        int m = mb + fm*16 + l15;
        bf16* row = outb + (size_t)m * N;
#pragma unroll
        for (int fn = 0; fn < 4; ++fn) {
            int n = nb + fn*16 + quad*4;
            float4 bv = *(const float4*)(bias + n);
            float v0 = acc[fm][fn][0] + bv.x;
            float v1 = acc[fm][fn][1] + bv.y;
            float v2 = acc[fm][fn][2] + bv.z;
            float v3 = acc[fm][fn][3] + bv.w;
            if (isq) { v0 *= QSCALE; v1 *= QSCALE; v2 *= QSCALE; v3 *= QSCALE; }
            *(uint2*)(row + n) = make_uint2(pack_rne(v0, v1), pack_rne(v2, v3));
        }
    }
}

// ---------------- GEMM: C = A @ B^T (128x128 tile) -- used for proj ----------------
template<int MODE>
__global__ __launch_bounds__(256) void gemm_bt(
    const bf16* __restrict__ A, const bf16* __restrict__ B, const float* __restrict__ bias,
    int M, int N, int K,
    bf16* __restrict__ outb, bf16* __restrict__ vTo, float* __restrict__ outf)
{
    __shared__ __align__(16) bf16 As[2][128*64];
    __shared__ __align__(16) bf16 Bs[2][128*64];

    const int t = threadIdx.x;
    const int lane = t & 63, wave = t >> 6;
    const int l15 = lane & 15, quad = lane >> 4;
    const int wm = (wave >> 1) * 64, wn = (wave & 1) * 64;

    constexpr int GX  = (MODE == 0) ? (QKVN/128) : (DIM/128);
    constexpr int NWG = GX * (MROWS/128);
    constexpr int CHUNK = NWG / 8;
    int lin = blockIdx.y * GX + blockIdx.x;
    lin = (lin & 7) * CHUNK + (lin >> 3);
    const int m0 = (lin / GX) * 128, n0 = (lin % GX) * 128;

    floatx4 acc[4][4];
    floatx4 zero = {0.f, 0.f, 0.f, 0.f};
    for (int i = 0; i < 4; ++i)
        for (int j = 0; j < 4; ++j)
            acc[i][j] = zero;

    const int trow = t >> 3;
    const int gc = ((t & 7) ^ (trow & 7)) << 3;
    const bf16* aA = A + (size_t)(m0 + trow) * K + gc;
    const bf16* aB = B + (size_t)(n0 + trow) * K + gc;
    const int lb = wave * 512;

    for (int s = 0; s < 4; ++s) {
        async_ld16(aA + (size_t)s*32*K, &As[0][s*2048 + lb]);
        async_ld16(aB + (size_t)s*32*K, &Bs[0][s*2048 + lb]);
    }

    const int sw = l15 & 7;
    const int nit = K >> 6;
    for (int kt = 0; kt < nit; ++kt) {
        const int cur = kt & 1;
        __syncthreads();
        if (kt + 1 < nit) {
            const bf16* pA = aA + (size_t)(kt+1)*64;
            const bf16* pB = aB + (size_t)(kt+1)*64;
            for (int s = 0; s < 4; ++s) {
                async_ld16(pA + (size_t)s*32*K, &As[cur^1][s*2048 + lb]);
                async_ld16(pB + (size_t)s*32*K, &Bs[cur^1][s*2048 + lb]);
            }
        }
        short8 af0[4], af1[4], bf0[4], bf1[4];
        for (int fm = 0; fm < 4; ++fm) {
            int base = (wm + fm*16 + l15) * 64 + ((quad ^ sw) << 3);
            af0[fm] = *(const short8*)(&As[cur][base]);
            af1[fm] = *(const short8*)(&As[cur][base ^ 32]);
        }
        for (int fn = 0; fn < 4; ++fn) {
            int base = (wn + fn*16 + l15) * 64 + ((quad ^ sw) << 3);
            bf0[fn] = *(const short8*)(&Bs[cur][base]);
            bf1[fn] = *(const short8*)(&Bs[cur][base ^ 32]);
        }
        for (int fm = 0; fm < 4; ++fm)
            for (int fn = 0; fn < 4; ++fn) {
                acc[fm][fn] = mfma16(bf0[fn], af0[fm], acc[fm][fn]);
                acc[fm][fn] = mfma16(bf1[fn], af1[fm], acc[fm][fn]);
            }
    }

    if (MODE == 0 && n0 >= 2*DIM) {
        bf16* S = &As[0][0] + wave * 2048;
        unsigned short* Su = (unsigned short*)S;
        const int bh   = (m0 / NN) * NH + ((n0 + wn) >> 6) - 24;
        const int tokb = (m0 % NN) + wm;
        const int dl = lane >> 2, cc = (lane & 3) * 16;
        for (int fn = 0; fn < 4; ++fn) {
            int nb = n0 + wn + fn*16 + quad*4;
            float4 bv = *(const float4*)(bias + nb);
            float bvr[4] = {bv.x, bv.y, bv.z, bv.w};
            for (int fm = 0; fm < 4; ++fm) {
#pragma unroll
                for (int r = 0; r < 4; ++r) {
                    float v = acc[fm][fn][r] + bvr[r];
                    Su[(quad*4 + r)*72 + fm*16 + l15] =
                        (unsigned short)(__float_as_uint(v) >> 16);
                }
            }
            uint4 r0 = *(const uint4*)(S + dl*72 + cc);
            uint4 r1 = *(const uint4*)(S + dl*72 + cc + 8);
            bf16* dst = vTo + ((size_t)bh * HD + fn*16 + dl) * NN + tokb + cc;
            *(uint4*)dst = r0;
            *(uint4*)(dst + 8) = r1;
        }
        return;
    }

    for (int fm = 0; fm < 4; ++fm) {
        int m = m0 + wm + fm*16 + l15;
        if (MODE == 0) {
            bf16* row = outb + (size_t)m * N;
            for (int fn = 0; fn < 4; ++fn) {
                int n = n0 + wn + fn*16 + quad*4;
                float4 bv = *(const float4*)(bias + n);
                float v0 = acc[fm][fn][0] + bv.x;
                float v1 = acc[fm][fn][1] + bv.y;
                float v2 = acc[fm][fn][2] + bv.z;
                float v3 = acc[fm][fn][3] + bv.w;
                if (n < DIM) {
                    v0 *= QSCALE; v1 *= QSCALE; v2 *= QSCALE; v3 *= QSCALE;
                }
                *(uint2*)(row + n) = make_uint2(pack_rne(v0, v1), pack_rne(v2, v3));
            }
        } else {
            float* row = outf + (size_t)m * N;
            for (int fn = 0; fn < 4; ++fn) {
                int n = n0 + wn + fn*16 + quad*4;
                float4 bv = *(const float4*)(bias + n);
                float4 v;
                v.x = acc[fm][fn][0] + bv.x;
                v.y = acc[fm][fn][1] + bv.y;
                v.z = acc[fm][fn][2] + bv.z;
                v.w = acc[fm][fn][3] + bv.w;
                *(float4*)(row + n) = v;
            }
        }
    }
}

// ---------------- fused attention v7: staged LDS, BK=64 ----------------
__global__ __launch_bounds__(256) void attn_kernel(
    const bf16* __restrict__ qkv, const bf16* __restrict__ vT,
    const float* __restrict__ w2, bf16* __restrict__ ao)
{
    int lin = blockIdx.y * BH + blockIdx.x;
    int j = lin >> 3;
    const int bh = (lin & 7) + 8 * (j / 10);
    const int qt = j % 10;
    const int b = bh / NH, h = bh - b * NH;
    const int t = threadIdx.x;
    const int wave = t >> 6, lane = t & 63;
    const int l15 = lane & 15, quad = lane >> 4;
    const int qrow0 = qt * 64 + wave * 16;

    float w0 = w2[0], w1 = w2[1];
    float wmx = fmaxf(w0, w1);
    float e0 = __expf(w0 - wmx), e1 = __expf(w1 - wmx);
    float ws0 = e0 / (e0 + e1);
    float ws1 = (1.0f - ws0) * LN2SQ;

    __shared__ __align__(16) bf16 Kb[2][64*64];
    __shared__ __align__(16) bf16 Vb[2][64*64];
    __shared__ __align__(16) bf16 Ps[4][16*72];
    __shared__ __align__(16) bf16 Pr[4][16*72];

    const bf16* kb = qkv + (size_t)(b*NN)*QKVN + DIM + h*HD;
    const bf16* vb = vT + (size_t)bh * HD * NN;

    const bf16* qr = qkv + (size_t)(b*NN + qrow0 + l15) * QKVN + h*HD;
    short8 aq0 = *(const short8*)(qr + quad*8);
    short8 aq1 = *(const short8*)(qr + 32 + quad*8);

    const int srow = t >> 3;
    const int gc   = ((lane & 7) ^ (lane >> 3)) << 3;
    const bf16* kst = kb + (size_t)srow * QKVN + gc;
    const bf16* vst = vb + (size_t)srow * NN + gc;
    const int lb0 = (wave * 64) * 8;
    const int lb1 = (256 + wave * 64) * 8;

    async_ld16(kst,                     &Kb[0][lb0]);
    async_ld16(kst + (size_t)32 * QKVN, &Kb[0][lb1]);
    async_ld16(vst,                     &Vb[0][lb0]);
    async_ld16(vst + (size_t)32 * NN,   &Vb[0][lb1]);

    floatx4 zero = {0.f, 0.f, 0.f, 0.f};
    floatx4 accS[4], accR[4];
    for (int i = 0; i < 4; ++i) { accS[i] = zero; accR[i] = zero; }
    float lsum = 0.f;

    const int sw = l15 & 7;
    const int fbase = l15 * 64 + ((quad ^ sw) << 3);

    unsigned* PsW = (unsigned*)&Ps[wave][0];
    unsigned* PrW = (unsigned*)&Pr[wave][0];
    const int wb = l15*36 + quad*2;
    const bf16* PsR = &Ps[wave][l15*72 + quad*8];
    const bf16* PrR = &Pr[wave][l15*72 + quad*8];

#pragma unroll 2
    for (int kt = 0; kt < 10; ++kt) {
        const int cur = kt & 1;
        __syncthreads();
        if (kt + 1 < 10) {
            kst += (size_t)64 * QKVN;
            vst += 64;
            async_ld16(kst,                     &Kb[cur^1][lb0]);
            async_ld16(kst + (size_t)32 * QKVN, &Kb[cur^1][lb1]);
            async_ld16(vst,                     &Vb[cur^1][lb0]);
            async_ld16(vst + (size_t)32 * NN,   &Vb[cur^1][lb1]);
        }

        const bf16* Kc = &Kb[cur][0];
        const bf16* Vc = &Vb[cur][0];

        floatx4 s[4];
        for (int I = 0; I < 4; ++I) {
            short8 aklo = *(const short8*)(Kc + fbase + I*1024);
            short8 akhi = *(const short8*)(Kc + ((fbase + I*1024) ^ 32));
            s[I] = zero;
            s[I] = mfma16(aklo, aq0, s[I]);
            s[I] = mfma16(akhi, aq1, s[I]);
        }

        short8 bvlo[4], bvhi[4];
        for (int dt = 0; dt < 4; ++dt) {
            bvlo[dt] = *(const short8*)(Vc + fbase + dt*1024);
            bvhi[dt] = *(const short8*)(Vc + ((fbase + dt*1024) ^ 32));
        }

        for (int I = 0; I < 4; ++I) {
            float ex[4], rq[4];
            for (int r = 0; r < 4; ++r) {
                ex[r] = fexp2(s[I][r]);
                float m = fmaxf(s[I][r], 0.f);
                rq[r] = m * m;
                lsum += ex[r];
            }
            *(uint2*)(PsW + wb + I*8) = make_uint2(pack_trunc(ex[0],ex[1]), pack_trunc(ex[2],ex[3]));
            *(uint2*)(PrW + wb + I*8) = make_uint2(pack_trunc(rq[0],rq[1]), pack_trunc(rq[2],rq[3]));
        }

        short8 paSlo = *(const short8*)PsR;
        short8 paShi = *(const short8*)(PsR + 32);
        short8 paRlo = *(const short8*)PrR;
        short8 paRhi = *(const short8*)(PrR + 32);

        for (int dt = 0; dt < 4; ++dt) {
            accS[dt] = mfma16(paSlo, bvlo[dt], accS[dt]);
            accS[dt] = mfma16(paShi, bvhi[dt], accS[dt]);
            accR[dt] = mfma16(paRlo, bvlo[dt], accR[dt]);
            accR[dt] = mfma16(paRhi, bvhi[dt], accR[dt]);
        }
    }

    lsum += __shfl_xor(lsum, 16);
    lsum += __shfl_xor(lsum, 32);
    float invq[4];
    for (int r = 0; r < 4; ++r)
        invq[r] = 1.0f / __shfl(lsum, quad*4 + r);

    for (int dt = 0; dt < 4; ++dt) {
        for (int r = 0; r < 4; ++r) {
            float v = ws0 * accS[dt][r] * invq[r] + ws1 * accR[dt][r];
            int tok = qrow0 + quad*4 + r;
            ao[((size_t)(b * NN + tok)) * DIM + h * HD + dt*16 + l15] = __float2bfloat16(v);
        }
    }
}

// ---------------- launch ----------------

extern "C" void kernel_launch(void* const* d_in, const int* in_sizes, int n_in,
                              void* d_out, int out_size, void* d_ws, size_t ws_size,
                              hipStream_t stream) {
    const float* x      = (const float*)d_in[0];
    const float* qkv_w  = (const float*)d_in[1];
    const float* qkv_b  = (const float*)d_in[2];
    const float* proj_w = (const float*)d_in[3];
    const float* proj_b = (const float*)d_in[4];
    const float* w2     = (const float*)d_in[5];
    float* out = (float*)d_out;

    bf16* xb   = (bf16*)d_ws;                       // 10240*768   (reused as ao later)
    bf16* qwT  = xb   + (size_t)MROWS * DIM;        // 2304*768
    bf16* pwT  = qwT  + (size_t)QKVN * DIM;         // 768*768
    bf16* qkvb = pwT  + (size_t)DIM * DIM;          // 10240*2304 (V cols unused)
    bf16* vT   = qkvb + (size_t)MROWS * QKVN;       // 192*64*640
    bf16* ao   = xb;                                 // alias: xb dead after qkv gemm

    prep_all<<<CVT_BLK + TRQ_BLK + TRP_BLK, 256, 0, stream>>>(
        x, qkv_w, proj_w, xb, qwT, pwT);

    gemm_qkv256<<<dim3(QKVN / 256, MROWS / 256), 512, 0, stream>>>(
        xb, qwT, qkv_b, qkvb, vT);

    attn_kernel<<<dim3(BH, NN / 64), 256, 0, stream>>>(qkvb, vT, w2, ao);

    gemm_bt<1><<<dim3(DIM / 128, MROWS / 128), 256, 0, stream>>>(
        ao, pwT, proj_b, MROWS, DIM, DIM, nullptr, nullptr, out);
}

// Round 3
// 225.285 us; speedup vs baseline: 1.0093x; 1.0093x over previous
//
#include <hip/hip_runtime.h>
#include <hip/hip_bf16.h>

typedef __attribute__((ext_vector_type(8))) short short8;
typedef __attribute__((ext_vector_type(4))) float floatx4;
typedef __hip_bfloat16 bf16;

#define DIM 768
#define NH 12
#define HD 64
#define BB 16
#define NN 640
#define BH (BB*NH)          // 192
#define MROWS (BB*NN)       // 10240
#define QKVN (3*DIM)        // 2304
#define QSCALE 0.18033688011113205f   // 0.125 * log2(e)
#define LN2SQ 0.4804530139182014f     // ln(2)^2

#define CVT_BLK (MROWS*DIM/4/256)     // 7680
#define TRQ_BLK ((QKVN/32)*(DIM/32))  // 1728
#define TRP_BLK ((DIM/32)*(DIM/32))   // 576

__device__ __forceinline__ floatx4 mfma16(short8 a, short8 b, floatx4 c) {
    return __builtin_amdgcn_mfma_f32_16x16x32_bf16(a, b, c, 0, 0, 0);
}

// async global->LDS, 16B per lane; lds dest = wave-uniform base + lane*16
__device__ __forceinline__ void async_ld16(const bf16* g, bf16* l) {
    __builtin_amdgcn_global_load_lds(
        (const __attribute__((address_space(1))) void*)g,
        (__attribute__((address_space(3))) void*)l, 16, 0, 0);
}

// truncate two f32 to bf16 and pack: lo16 = a, hi16 = b  (one v_perm_b32)
__device__ __forceinline__ unsigned pack_trunc(float a, float b) {
    return __builtin_amdgcn_perm(__float_as_uint(b), __float_as_uint(a), 0x07060302u);
}

// RNE two f32 -> packed bf16x2 (matches __float2bfloat16 numerics)
__device__ __forceinline__ unsigned pack_rne(float a, float b) {
    unsigned sa = (unsigned)__bfloat16_as_ushort(__float2bfloat16(a));
    unsigned sb = (unsigned)__bfloat16_as_ushort(__float2bfloat16(b));
    return sa | (sb << 16);
}

__device__ __forceinline__ float fexp2(float x) {
#if __has_builtin(__builtin_amdgcn_exp2f)
    return __builtin_amdgcn_exp2f(x);
#else
    return exp2f(x);
#endif
}

// ---------------- fused prep: x->bf16 + both weight transposes ----------------
__global__ void prep_all(const float* __restrict__ x,
                         const float* __restrict__ qkv_w,
                         const float* __restrict__ proj_w,
                         bf16* __restrict__ xb,
                         bf16* __restrict__ qwT,
                         bf16* __restrict__ pwT)
{
    __shared__ float tile[32][33];
    const int id = blockIdx.x;
    const int t = threadIdx.x;

    if (id < CVT_BLK) {
        int i = id * 256 + t;
        float4 v = ((const float4*)x)[i];
        *(uint2*)(xb + (size_t)i * 4) =
            make_uint2(pack_rne(v.x, v.y), pack_rne(v.z, v.w));
        return;
    }

    const float* src; bf16* dst; int C, bx, by;
    if (id < CVT_BLK + TRQ_BLK) {
        int j = id - CVT_BLK;
        bx = j % (QKVN/32); by = j / (QKVN/32);
        src = qkv_w; dst = qwT; C = QKVN;
    } else {
        int j = id - CVT_BLK - TRQ_BLK;
        bx = j % (DIM/32); by = j / (DIM/32);
        src = proj_w; dst = pwT; C = DIM;
    }
    const int R = DIM;
    const int tx = t & 31, ty = t >> 5;
    for (int j = 0; j < 4; ++j)
        tile[ty + j*8][tx] = src[(size_t)(by*32 + ty + j*8) * C + bx*32 + tx];
    __syncthreads();
    for (int j = 0; j < 4; ++j)
        dst[(size_t)(bx*32 + ty + j*8) * R + by*32 + tx] = __float2bfloat16(tile[tx][ty + j*8]);
}

// ---------------- GEMM: 256x128 tile, 4-phase counted-vmcnt schedule ----------------
// C = A @ B^T, A [M][768] bf16, B [N][768] bf16. 512 thr / 8 waves (4M x 2N),
// per-wave 64x64 output (acc[4][4]). BK=64, 2-deep LDS (96 KiB), grid NWG blocks
// (720 qkv / 240 proj) -> 94% CU quantization (vs 70% for 256x256's 360).
// Iter = 2 K-tiles = 4 phases x 16 MFMA. A buffer is FULLY frag-read in its
// first phase (P0 for buf0, P2 for buf1) -> widest overwrite windows:
//   P0: read all frags buf0 | bar | lgkm | MFMA fm0/1 | bar
//   P1: issue A(t+2->buf0)x4 | MFMA fm2/3 (held regs) | vmcnt(4) | bar
//   P2: read all frags buf1, issue B(t+2->buf0)x2 | bar | lgkm | MFMA fm0/1 | bar
//   P3: issue A,B(t+3->buf1)x6 | MFMA fm2/3 | vmcnt(6) | bar
// Ledger (per-thread outstanding, steady): enter=6(t+1) -> P1 +4=10, vm4 drains
// t+1 (needed by P2) -> P2 +2=6 -> P3 +6=12, vm6 drains t+2 (needed by next P0),
// keeps t+3 in flight. Every buffer overwrite issues >=1 trailing barrier after
// that region's last ds_read completed (lgkm precedes MFMA precedes barrier).
template<int MODE>
__global__ __launch_bounds__(512, 2) void gemm256(
    const bf16* __restrict__ A, const bf16* __restrict__ B, const float* __restrict__ bias,
    bf16* __restrict__ outb, bf16* __restrict__ vTo, float* __restrict__ outf)
{
    constexpr int K = DIM;                       // 768: 12 K-tiles, 6 iters
    constexpr int N = (MODE == 0) ? QKVN : DIM;  // 2304 / 768
    constexpr int GX = N / 128;                  // 18 / 6
    constexpr int NWG = GX * (MROWS / 256);      // 720 / 240
    constexpr int CHUNK = NWG / 8;               // 90 / 30

    __shared__ __align__(16) bf16 As[2][256*64];   // 64 KiB
    __shared__ __align__(16) bf16 Bs[2][128*64];   // 32 KiB

    const int t = threadIdx.x;
    const int lane = t & 63, wave = t >> 6;
    const int l15 = lane & 15, quad = lane >> 4;
    const int wm = wave >> 1;        // M quarter (0..3), 64 rows
    const int wn = wave & 1;         // N half (0..1), 64 cols

    // XCD-chunked bijective swizzle (NWG % 8 == 0)
    int lin = blockIdx.x;
    lin = (lin & 7) * CHUNK + (lin >> 3);
    const int m0 = (lin / GX) * 256, n0 = (lin % GX) * 128;

    floatx4 acc[4][4];
    floatx4 zero = {0.f, 0.f, 0.f, 0.f};
#pragma unroll
    for (int i = 0; i < 4; ++i)
#pragma unroll
        for (int j = 0; j < 4; ++j)
            acc[i][j] = zero;

    // staging: call s covers rows s*64+trow; slot t&7, source chunk slot^(row&7)
    const int trow = t >> 3;
    const int gc = ((t & 7) ^ (trow & 7)) << 3;
    const bf16* Ag = A + (size_t)(m0 + trow) * K + gc;
    const bf16* Bg = B + (size_t)(n0 + trow) * K + gc;
    const int tb = t * 8;

#define STG_A(buf,s,tcol) async_ld16(Ag + (size_t)(s)*64*K + (tcol), &As[buf][(s)*4096 + tb])
#define STG_B(buf,s,tcol) async_ld16(Bg + (size_t)(s)*64*K + (tcol), &Bs[buf][(s)*4096 + tb])

    // frag offsets (swizzled): row r, k-half kh chunk c=quad+4*kh -> slot c^(r&7)
    const int sw8 = (quad ^ (l15 & 7)) << 3;
    const int aoff = (wm*64 + l15) * 64 + sw8;    // + fm*1024 ; ^32 = k-half 1
    const int boff = (wn*64 + l15) * 64 + sw8;    // + fn*1024

    short8 afr[4][2], bfr[4][2];

#define RD_FRAGS(buf) do { \
    _Pragma("unroll") \
    for (int f = 0; f < 4; ++f) { \
        afr[f][0] = *(const short8*)&As[buf][aoff + f*1024]; \
        afr[f][1] = *(const short8*)&As[buf][(aoff + f*1024) ^ 32]; \
        bfr[f][0] = *(const short8*)&Bs[buf][boff + f*1024]; \
        bfr[f][1] = *(const short8*)&Bs[buf][(boff + f*1024) ^ 32]; \
    } } while (0)

#define MFMA_HALF(q) do { \
    __builtin_amdgcn_s_setprio(1); \
    _Pragma("unroll") \
    for (int fn = 0; fn < 4; ++fn) { \
        acc[2*(q)][fn]   = mfma16(bfr[fn][0], afr[2*(q)][0],   acc[2*(q)][fn]); \
        acc[2*(q)+1][fn] = mfma16(bfr[fn][0], afr[2*(q)+1][0], acc[2*(q)+1][fn]); \
    } \
    _Pragma("unroll") \
    for (int fn = 0; fn < 4; ++fn) { \
        acc[2*(q)][fn]   = mfma16(bfr[fn][1], afr[2*(q)][1],   acc[2*(q)][fn]); \
        acc[2*(q)+1][fn] = mfma16(bfr[fn][1], afr[2*(q)+1][1], acc[2*(q)+1][fn]); \
    } \
    __builtin_amdgcn_s_setprio(0); \
} while (0)

    // prologue: tiles 0 (buf0) and 1 (buf1); vm6 -> t0 landed, t1 in flight
    STG_A(0,0,0); STG_A(0,1,0); STG_A(0,2,0); STG_A(0,3,0);
    STG_B(0,0,0); STG_B(0,1,0);
    STG_A(1,0,64); STG_A(1,1,64); STG_A(1,2,64); STG_A(1,3,64);
    STG_B(1,0,64); STG_B(1,1,64);
    asm volatile("s_waitcnt vmcnt(6)" ::: "memory");
    __builtin_amdgcn_s_barrier();

    for (int it = 0; it < 6; ++it) {
        const int kb = it * 128;
        const bool more = (it < 5);
        // P0: compute buf0 (tile 2it), fm0/1
        RD_FRAGS(0);
        __builtin_amdgcn_s_barrier();
        asm volatile("s_waitcnt lgkmcnt(0)" ::: "memory");
        __builtin_amdgcn_sched_barrier(0);
        MFMA_HALF(0);
        __builtin_amdgcn_s_barrier();
        // P1: stage A(t+2 -> buf0); fm2/3 from held regs
        if (more) { STG_A(0,0,kb+128); STG_A(0,1,kb+128); STG_A(0,2,kb+128); STG_A(0,3,kb+128); }
        MFMA_HALF(1);
        __builtin_amdgcn_sched_barrier(0);
        if (more) { asm volatile("s_waitcnt vmcnt(4)" ::: "memory"); }
        else      { asm volatile("s_waitcnt vmcnt(0)" ::: "memory"); }
        __builtin_amdgcn_s_barrier();
        // P2: compute buf1 (tile 2it+1), fm0/1; stage B(t+2 -> buf0)
        RD_FRAGS(1);
        if (more) { STG_B(0,0,kb+128); STG_B(0,1,kb+128); }
        __builtin_amdgcn_s_barrier();
        asm volatile("s_waitcnt lgkmcnt(0)" ::: "memory");
        __builtin_amdgcn_sched_barrier(0);
        MFMA_HALF(0);
        __builtin_amdgcn_s_barrier();
        // P3: stage A,B(t+3 -> buf1); fm2/3
        if (more) { STG_A(1,0,kb+192); STG_A(1,1,kb+192); STG_A(1,2,kb+192); STG_A(1,3,kb+192);
                    STG_B(1,0,kb+192); STG_B(1,1,kb+192); }
        MFMA_HALF(1);
        __builtin_amdgcn_sched_barrier(0);
        if (more) { asm volatile("s_waitcnt vmcnt(6)" ::: "memory"); }
        __builtin_amdgcn_s_barrier();
    }
#undef RD_FRAGS
#undef MFMA_HALF
#undef STG_A
#undef STG_B

    // ---- epilogue: acc[fm][fn][r] = C[m = m0+wm*64+fm*16+l15][n = n0+wn*64+fn*16+quad*4+r]
    const int mb = m0 + wm * 64;
    const int nb = n0 + wn * 64;

    if (MODE == 0 && n0 >= 2*DIM) {
        // V block: wave's 64-col span = one head; 64-row span never crosses a
        // batch boundary (64 | 640). LDS transpose scratch (stride 72), then
        // coalesced uint4 stores to vT[bh][d][tok]. All loads drained (vm0 at
        // it=5 P1, nothing issued after); all waves past final barrier.
        bf16* S = &As[0][0] + wave * 2048;
        unsigned short* Su = (unsigned short*)S;
        const int head = ((nb - 2*DIM) >> 6);
        const int bh = (mb / NN) * NH + head;
        const int tokb = mb % NN;
        const int dl = lane >> 2, cc = (lane & 3) * 16;
#pragma unroll
        for (int fn = 0; fn < 4; ++fn) {
            int nq = nb + fn*16 + quad*4;
            float4 bv = *(const float4*)(bias + nq);
            float bvr[4] = {bv.x, bv.y, bv.z, bv.w};
#pragma unroll
            for (int fm = 0; fm < 4; ++fm) {
#pragma unroll
                for (int r = 0; r < 4; ++r) {
                    float v = acc[fm][fn][r] + bvr[r];
                    Su[(quad*4 + r)*72 + fm*16 + l15] =
                        (unsigned short)(__float_as_uint(v) >> 16);
                }
            }
            // per-wave scratch: in-wave lgkmcnt ordering suffices
            uint4 r0 = *(const uint4*)(S + dl*72 + cc);
            uint4 r1 = *(const uint4*)(S + dl*72 + cc + 8);
            int d = fn*16 + dl;
            bf16* dst = vTo + ((size_t)bh * HD + d) * NN + tokb + cc;
            *(uint4*)dst = r0;
            *(uint4*)(dst + 8) = r1;
        }
        return;
    }

    if (MODE == 0) {
        const bool isq = (n0 < DIM);
#pragma unroll
        for (int fm = 0; fm < 4; ++fm) {
            int m = mb + fm*16 + l15;
            bf16* row = outb + (size_t)m * N;
#pragma unroll
            for (int fn = 0; fn < 4; ++fn) {
                int n = nb + fn*16 + quad*4;
                float4 bv = *(const float4*)(bias + n);
                float v0 = acc[fm][fn][0] + bv.x;
                float v1 = acc[fm][fn][1] + bv.y;
                float v2 = acc[fm][fn][2] + bv.z;
                float v3 = acc[fm][fn][3] + bv.w;
                if (isq) { v0 *= QSCALE; v1 *= QSCALE; v2 *= QSCALE; v3 *= QSCALE; }
                *(uint2*)(row + n) = make_uint2(pack_rne(v0, v1), pack_rne(v2, v3));
            }
        }
    } else {
#pragma unroll
        for (int fm = 0; fm < 4; ++fm) {
            int m = mb + fm*16 + l15;
            float* row = outf + (size_t)m * N;
#pragma unroll
            for (int fn = 0; fn < 4; ++fn) {
                int n = nb + fn*16 + quad*4;
                float4 bv = *(const float4*)(bias + n);
                float4 v;
                v.x = acc[fm][fn][0] + bv.x;
                v.y = acc[fm][fn][1] + bv.y;
                v.z = acc[fm][fn][2] + bv.z;
                v.w = acc[fm][fn][3] + bv.w;
                *(float4*)(row + n) = v;
            }
        }
    }
}

// ---------------- fused attention v7: staged LDS, BK=64 ----------------
__global__ __launch_bounds__(256) void attn_kernel(
    const bf16* __restrict__ qkv, const bf16* __restrict__ vT,
    const float* __restrict__ w2, bf16* __restrict__ ao)
{
    int lin = blockIdx.y * BH + blockIdx.x;
    int j = lin >> 3;
    const int bh = (lin & 7) + 8 * (j / 10);
    const int qt = j % 10;
    const int b = bh / NH, h = bh - b * NH;
    const int t = threadIdx.x;
    const int wave = t >> 6, lane = t & 63;
    const int l15 = lane & 15, quad = lane >> 4;
    const int qrow0 = qt * 64 + wave * 16;

    float w0 = w2[0], w1 = w2[1];
    float wmx = fmaxf(w0, w1);
    float e0 = __expf(w0 - wmx), e1 = __expf(w1 - wmx);
    float ws0 = e0 / (e0 + e1);
    float ws1 = (1.0f - ws0) * LN2SQ;

    __shared__ __align__(16) bf16 Kb[2][64*64];
    __shared__ __align__(16) bf16 Vb[2][64*64];
    __shared__ __align__(16) bf16 Ps[4][16*72];
    __shared__ __align__(16) bf16 Pr[4][16*72];

    const bf16* kb = qkv + (size_t)(b*NN)*QKVN + DIM + h*HD;
    const bf16* vb = vT + (size_t)bh * HD * NN;

    const bf16* qr = qkv + (size_t)(b*NN + qrow0 + l15) * QKVN + h*HD;
    short8 aq0 = *(const short8*)(qr + quad*8);
    short8 aq1 = *(const short8*)(qr + 32 + quad*8);

    const int srow = t >> 3;
    const int gc   = ((lane & 7) ^ (lane >> 3)) << 3;
    const bf16* kst = kb + (size_t)srow * QKVN + gc;
    const bf16* vst = vb + (size_t)srow * NN + gc;
    const int lb0 = (wave * 64) * 8;
    const int lb1 = (256 + wave * 64) * 8;

    async_ld16(kst,                     &Kb[0][lb0]);
    async_ld16(kst + (size_t)32 * QKVN, &Kb[0][lb1]);
    async_ld16(vst,                     &Vb[0][lb0]);
    async_ld16(vst + (size_t)32 * NN,   &Vb[0][lb1]);

    floatx4 zero = {0.f, 0.f, 0.f, 0.f};
    floatx4 accS[4], accR[4];
    for (int i = 0; i < 4; ++i) { accS[i] = zero; accR[i] = zero; }
    float lsum = 0.f;

    const int sw = l15 & 7;
    const int fbase = l15 * 64 + ((quad ^ sw) << 3);

    unsigned* PsW = (unsigned*)&Ps[wave][0];
    unsigned* PrW = (unsigned*)&Pr[wave][0];
    const int wb = l15*36 + quad*2;
    const bf16* PsR = &Ps[wave][l15*72 + quad*8];
    const bf16* PrR = &Pr[wave][l15*72 + quad*8];

#pragma unroll 2
    for (int kt = 0; kt < 10; ++kt) {
        const int cur = kt & 1;
        __syncthreads();
        if (kt + 1 < 10) {
            kst += (size_t)64 * QKVN;
            vst += 64;
            async_ld16(kst,                     &Kb[cur^1][lb0]);
            async_ld16(kst + (size_t)32 * QKVN, &Kb[cur^1][lb1]);
            async_ld16(vst,                     &Vb[cur^1][lb0]);
            async_ld16(vst + (size_t)32 * NN,   &Vb[cur^1][lb1]);
        }

        const bf16* Kc = &Kb[cur][0];
        const bf16* Vc = &Vb[cur][0];

        floatx4 s[4];
        for (int I = 0; I < 4; ++I) {
            short8 aklo = *(const short8*)(Kc + fbase + I*1024);
            short8 akhi = *(const short8*)(Kc + ((fbase + I*1024) ^ 32));
            s[I] = zero;
            s[I] = mfma16(aklo, aq0, s[I]);
            s[I] = mfma16(akhi, aq1, s[I]);
        }

        short8 bvlo[4], bvhi[4];
        for (int dt = 0; dt < 4; ++dt) {
            bvlo[dt] = *(const short8*)(Vc + fbase + dt*1024);
            bvhi[dt] = *(const short8*)(Vc + ((fbase + dt*1024) ^ 32));
        }

        for (int I = 0; I < 4; ++I) {
            float ex[4], rq[4];
            for (int r = 0; r < 4; ++r) {
                ex[r] = fexp2(s[I][r]);
                float m = fmaxf(s[I][r], 0.f);
                rq[r] = m * m;
                lsum += ex[r];
            }
            *(uint2*)(PsW + wb + I*8) = make_uint2(pack_trunc(ex[0],ex[1]), pack_trunc(ex[2],ex[3]));
            *(uint2*)(PrW + wb + I*8) = make_uint2(pack_trunc(rq[0],rq[1]), pack_trunc(rq[2],rq[3]));
        }

        short8 paSlo = *(const short8*)PsR;
        short8 paShi = *(const short8*)(PsR + 32);
        short8 paRlo = *(const short8*)PrR;
        short8 paRhi = *(const short8*)(PrR + 32);

        for (int dt = 0; dt < 4; ++dt) {
            accS[dt] = mfma16(paSlo, bvlo[dt], accS[dt]);
            accS[dt] = mfma16(paShi, bvhi[dt], accS[dt]);
            accR[dt] = mfma16(paRlo, bvlo[dt], accR[dt]);
            accR[dt] = mfma16(paRhi, bvhi[dt], accR[dt]);
        }
    }

    lsum += __shfl_xor(lsum, 16);
    lsum += __shfl_xor(lsum, 32);
    float invq[4];
    for (int r = 0; r < 4; ++r)
        invq[r] = 1.0f / __shfl(lsum, quad*4 + r);

    for (int dt = 0; dt < 4; ++dt) {
        for (int r = 0; r < 4; ++r) {
            float v = ws0 * accS[dt][r] * invq[r] + ws1 * accR[dt][r];
            int tok = qrow0 + quad*4 + r;
            ao[((size_t)(b * NN + tok)) * DIM + h * HD + dt*16 + l15] = __float2bfloat16(v);
        }
    }
}

// ---------------- launch ----------------

extern "C" void kernel_launch(void* const* d_in, const int* in_sizes, int n_in,
                              void* d_out, int out_size, void* d_ws, size_t ws_size,
                              hipStream_t stream) {
    const float* x      = (const float*)d_in[0];
    const float* qkv_w  = (const float*)d_in[1];
    const float* qkv_b  = (const float*)d_in[2];
    const float* proj_w = (const float*)d_in[3];
    const float* proj_b = (const float*)d_in[4];
    const float* w2     = (const float*)d_in[5];
    float* out = (float*)d_out;

    bf16* xb   = (bf16*)d_ws;                       // 10240*768   (reused as ao later)
    bf16* qwT  = xb   + (size_t)MROWS * DIM;        // 2304*768
    bf16* pwT  = qwT  + (size_t)QKVN * DIM;         // 768*768
    bf16* qkvb = pwT  + (size_t)DIM * DIM;          // 10240*2304 (V cols unused)
    bf16* vT   = qkvb + (size_t)MROWS * QKVN;       // 192*64*640
    bf16* ao   = xb;                                 // alias: xb dead after qkv gemm

    prep_all<<<CVT_BLK + TRQ_BLK + TRP_BLK, 256, 0, stream>>>(
        x, qkv_w, proj_w, xb, qwT, pwT);

    gemm256<0><<<dim3((QKVN/128) * (MROWS/256)), 512, 0, stream>>>(
        xb, qwT, qkv_b, qkvb, vT, nullptr);

    attn_kernel<<<dim3(BH, NN / 64), 256, 0, stream>>>(qkvb, vT, w2, ao);

    gemm256<1><<<dim3((DIM/128) * (MROWS/256)), 512, 0, stream>>>(
        ao, pwT, proj_b, nullptr, nullptr, out);
}

// Round 6
// 216.575 us; speedup vs baseline: 1.0499x; 1.0402x over previous
//
#include <hip/hip_runtime.h>
#include <hip/hip_bf16.h>

typedef __attribute__((ext_vector_type(8))) short short8;
typedef __attribute__((ext_vector_type(4))) float floatx4;
typedef __hip_bfloat16 bf16;

#define DIM 768
#define NH 12
#define HD 64
#define BB 16
#define NN 640
#define BH (BB*NH)          // 192
#define MROWS (BB*NN)       // 10240
#define QKVN (3*DIM)        // 2304
#define QSCALE 0.18033688011113205f   // 0.125 * log2(e)
#define LN2SQ 0.4804530139182014f     // ln(2)^2

#define CVT_BLK (MROWS*DIM/4/256)     // 7680
#define TRQ_BLK ((QKVN/32)*(DIM/32))  // 1728
#define TRP_BLK ((DIM/32)*(DIM/32))   // 576

__device__ __forceinline__ floatx4 mfma16(short8 a, short8 b, floatx4 c) {
    return __builtin_amdgcn_mfma_f32_16x16x32_bf16(a, b, c, 0, 0, 0);
}

// async global->LDS, 16B per lane; lds dest = wave-uniform base + lane*16
__device__ __forceinline__ void async_ld16(const bf16* g, bf16* l) {
    __builtin_amdgcn_global_load_lds(
        (const __attribute__((address_space(1))) void*)g,
        (__attribute__((address_space(3))) void*)l, 16, 0, 0);
}

// truncate two f32 to bf16 and pack: lo16 = a, hi16 = b  (one v_perm_b32)
__device__ __forceinline__ unsigned pack_trunc(float a, float b) {
    return __builtin_amdgcn_perm(__float_as_uint(b), __float_as_uint(a), 0x07060302u);
}

// RNE two f32 -> packed bf16x2 (matches __float2bfloat16 numerics)
__device__ __forceinline__ unsigned pack_rne(float a, float b) {
    unsigned sa = (unsigned)__bfloat16_as_ushort(__float2bfloat16(a));
    unsigned sb = (unsigned)__bfloat16_as_ushort(__float2bfloat16(b));
    return sa | (sb << 16);
}

__device__ __forceinline__ float fexp2(float x) {
#if __has_builtin(__builtin_amdgcn_exp2f)
    return __builtin_amdgcn_exp2f(x);
#else
    return exp2f(x);
#endif
}

// ---------------- fused prep: x->bf16 + both weight transposes ----------------
__global__ void prep_all(const float* __restrict__ x,
                         const float* __restrict__ qkv_w,
                         const float* __restrict__ proj_w,
                         bf16* __restrict__ xb,
                         bf16* __restrict__ qwT,
                         bf16* __restrict__ pwT)
{
    __shared__ float tile[32][33];
    const int id = blockIdx.x;
    const int t = threadIdx.x;

    if (id < CVT_BLK) {
        int i = id * 256 + t;
        float4 v = ((const float4*)x)[i];
        *(uint2*)(xb + (size_t)i * 4) =
            make_uint2(pack_rne(v.x, v.y), pack_rne(v.z, v.w));
        return;
    }

    const float* src; bf16* dst; int C, bx, by;
    if (id < CVT_BLK + TRQ_BLK) {
        int j = id - CVT_BLK;
        bx = j % (QKVN/32); by = j / (QKVN/32);
        src = qkv_w; dst = qwT; C = QKVN;
    } else {
        int j = id - CVT_BLK - TRQ_BLK;
        bx = j % (DIM/32); by = j / (DIM/32);
        src = proj_w; dst = pwT; C = DIM;
    }
    const int R = DIM;
    const int tx = t & 31, ty = t >> 5;
    for (int j = 0; j < 4; ++j)
        tile[ty + j*8][tx] = src[(size_t)(by*32 + ty + j*8) * C + bx*32 + tx];
    __syncthreads();
    for (int j = 0; j < 4; ++j)
        dst[(size_t)(bx*32 + ty + j*8) * R + by*32 + tx] = __float2bfloat16(tile[tx][ty + j*8]);
}

// ---------------- QKV GEMM: 256x192 tile, 6-phase counted-vmcnt ----------------
// C = A @ B^T, A [10240][768], B [2304][768] bf16. Grid 480 blocks (40x12) =
// 1.875 rounds of 256 CUs = 93.75% quantization. 512 thr / 8 waves (4M x 2N),
// per-wave 64x96 (acc[4][6]). BK=64, 2-deep LDS (112 KiB).
// Iter it handles tiles t0=2it (buf0, cols kb=it*128) and t1=2it+1 (buf1, kb+64).
// Staging: tile t+2 -> buf0 @ cols kb+128, tile t+3 -> buf1 @ cols kb+192.
// ACC NOTE (r5 bug): P3-P5 compute the SAME output cols from the next K-tile,
// so they accumulate into the SAME acc pairs 0/1/2 (never index acc by K-tile).
//   P0: rd A(8)+B01(4) buf0 | issue B(t+1->buf1)@kb+64 x3  | lg8|bar|lg0 | MFMA p0 | bar
//   P1: rd B23(4)           | issue A(t+2->buf0)@kb+128 x4 |     bar|lg0 | MFMA p1 | bar
//   P2: rd B45(4)           |                              |     bar|lg0 | MFMA p2 | vm4 | bar
//   P3: rd A(8)+B01(4) buf1 | issue B(t+2->buf0)@kb+128 x3 | lg8|bar|lg0 | MFMA p0 | bar
//   P4: rd B23(4)           | issue A(t+3->buf1)@kb+192 x4 |     bar|lg0 | MFMA p1 | bar
//   P5: rd B45(4)           |                              |     bar|lg0 | MFMA p2 | vm4 | bar
// Ledger (outstanding/thread): enter iter 4 (t+1.A) -> P0 +3=7 -> P1 +4=11,
// P2 vm4 drains 7 oldest = t+1 complete (before barrier -> P3 reads safe),
// keeps t+2.A -> P3 +3=7 -> P4 +4=11, P5 vm4 drains t+2, keeps t+3.A.
// Overwrites: each region's next stage issues >=1 trailing barrier after its
// last ds_read completed (lg0 precedes MFMA precedes barrier). Final iter:
// P2 uses vm0; P1/P3/P4 stages skipped; all columns stay < 768.
__global__ __launch_bounds__(512, 2) void gemm_qkv(
    const bf16* __restrict__ A, const bf16* __restrict__ B, const float* __restrict__ bias,
    bf16* __restrict__ outb, bf16* __restrict__ vTo)
{
    constexpr int K = DIM;           // 768: 12 K-tiles, 6 iters
    constexpr int N = QKVN;          // 2304
    constexpr int GX = N / 192;      // 12
    constexpr int NWG = GX * (MROWS / 256);  // 480
    constexpr int CHUNK = NWG / 8;   // 60

    __shared__ __align__(16) bf16 As[2][256*64];   // 64 KiB
    __shared__ __align__(16) bf16 Bs[2][192*64];   // 48 KiB

    const int t = threadIdx.x;
    const int lane = t & 63, wave = t >> 6;
    const int l15 = lane & 15, quad = lane >> 4;
    const int wm = wave >> 1;        // M quarter (0..3): rows wm*64
    const int wn = wave & 1;         // N half (0..1): cols wn*96

    int lin = blockIdx.x;
    lin = (lin & 7) * CHUNK + (lin >> 3);      // XCD-chunked bijection (480%8==0)
    const int m0 = (lin / GX) * 256, n0 = (lin % GX) * 192;

    floatx4 acc[4][6];
    floatx4 zero = {0.f, 0.f, 0.f, 0.f};
#pragma unroll
    for (int i = 0; i < 4; ++i)
#pragma unroll
        for (int j = 0; j < 6; ++j)
            acc[i][j] = zero;

    // staging: call s covers rows s*64+trow; slot t&7; chunk = slot^(row&7)
    const int trow = t >> 3;
    const int gc = ((t & 7) ^ (trow & 7)) << 3;
    const bf16* Ag = A + (size_t)(m0 + trow) * K + gc;
    const bf16* Bg = B + (size_t)(n0 + trow) * K + gc;
    const int tb = t * 8;

#define STG_A(buf,s,tcol) async_ld16(Ag + (size_t)(s)*64*K + (tcol), &As[buf][(s)*4096 + tb])
#define STG_B(buf,s,tcol) async_ld16(Bg + (size_t)(s)*64*K + (tcol), &Bs[buf][(s)*4096 + tb])

    // frag reads (swizzled): row r, chunk c -> slot c^(r&7); kh=1 via ^32
    const int sw8 = (quad ^ (l15 & 7)) << 3;
    const int aoff = (wm*64 + l15) * 64 + sw8;    // + fm*1024
    const int boff = (wn*96 + l15) * 64 + sw8;    // + fn*1024

    short8 afr[4][2], bfr[2][2];

#define RD_A(buf) do { \
    _Pragma("unroll") \
    for (int f = 0; f < 4; ++f) { \
        afr[f][0] = *(const short8*)&As[buf][aoff + f*1024]; \
        afr[f][1] = *(const short8*)&As[buf][(aoff + f*1024) ^ 32]; \
    } } while (0)

#define RD_B2(buf, fp) do { \
    bfr[0][0] = *(const short8*)&Bs[buf][boff + (2*(fp))*1024]; \
    bfr[0][1] = *(const short8*)&Bs[buf][(boff + (2*(fp))*1024) ^ 32]; \
    bfr[1][0] = *(const short8*)&Bs[buf][boff + (2*(fp)+1)*1024]; \
    bfr[1][1] = *(const short8*)&Bs[buf][(boff + (2*(fp)+1)*1024) ^ 32]; \
    } while (0)

#define MFMA16(fp) do { \
    __builtin_amdgcn_s_setprio(1); \
    _Pragma("unroll") \
    for (int fm = 0; fm < 4; ++fm) { \
        acc[fm][2*(fp)]   = mfma16(bfr[0][0], afr[fm][0], acc[fm][2*(fp)]); \
        acc[fm][2*(fp)+1] = mfma16(bfr[1][0], afr[fm][0], acc[fm][2*(fp)+1]); \
    } \
    _Pragma("unroll") \
    for (int fm = 0; fm < 4; ++fm) { \
        acc[fm][2*(fp)]   = mfma16(bfr[0][1], afr[fm][1], acc[fm][2*(fp)]); \
        acc[fm][2*(fp)+1] = mfma16(bfr[1][1], afr[fm][1], acc[fm][2*(fp)+1]); \
    } \
    __builtin_amdgcn_s_setprio(0); \
} while (0)

#define BAR_LG0() do { \
    __builtin_amdgcn_s_barrier(); \
    asm volatile("s_waitcnt lgkmcnt(0)" ::: "memory"); \
    __builtin_amdgcn_sched_barrier(0); \
} while (0)

    // prologue: t0 full (7 calls) + t1.A (4); vm4 -> t0 landed, t1.A in flight
    STG_A(0,0,0); STG_A(0,1,0); STG_A(0,2,0); STG_A(0,3,0);
    STG_B(0,0,0); STG_B(0,1,0); STG_B(0,2,0);
    STG_A(1,0,64); STG_A(1,1,64); STG_A(1,2,64); STG_A(1,3,64);
    asm volatile("s_waitcnt vmcnt(4)" ::: "memory");
    __builtin_amdgcn_s_barrier();

    for (int it = 0; it < 6; ++it) {
        const int kb = it * 128;
        const bool more = (it < 5);
        // ---- P0: buf0, acc pair 0; stage B(t+1 -> buf1) @ kb+64
        RD_A(0); RD_B2(0, 0);
        STG_B(1,0,kb+64); STG_B(1,1,kb+64); STG_B(1,2,kb+64);
        asm volatile("s_waitcnt lgkmcnt(8)" ::: "memory");
        BAR_LG0();
        MFMA16(0);
        __builtin_amdgcn_sched_barrier(0);
        __builtin_amdgcn_s_barrier();
        // ---- P1: buf0, acc pair 1; stage A(t+2 -> buf0) @ kb+128
        RD_B2(0, 1);
        if (more) { STG_A(0,0,kb+128); STG_A(0,1,kb+128); STG_A(0,2,kb+128); STG_A(0,3,kb+128); }
        BAR_LG0();
        MFMA16(1);
        __builtin_amdgcn_sched_barrier(0);
        __builtin_amdgcn_s_barrier();
        // ---- P2: buf0, acc pair 2; vm4 (drains t+1, keeps t+2.A)
        RD_B2(0, 2);
        BAR_LG0();
        MFMA16(2);
        __builtin_amdgcn_sched_barrier(0);
        if (more) { asm volatile("s_waitcnt vmcnt(4)" ::: "memory"); }
        else      { asm volatile("s_waitcnt vmcnt(0)" ::: "memory"); }
        __builtin_amdgcn_s_barrier();
        // ---- P3: buf1, acc pair 0; stage B(t+2 -> buf0) @ kb+128
        RD_A(1); RD_B2(1, 0);
        if (more) { STG_B(0,0,kb+128); STG_B(0,1,kb+128); STG_B(0,2,kb+128); }
        asm volatile("s_waitcnt lgkmcnt(8)" ::: "memory");
        BAR_LG0();
        MFMA16(0);
        __builtin_amdgcn_sched_barrier(0);
        __builtin_amdgcn_s_barrier();
        // ---- P4: buf1, acc pair 1; stage A(t+3 -> buf1) @ kb+192
        RD_B2(1, 1);
        if (more) { STG_A(1,0,kb+192); STG_A(1,1,kb+192); STG_A(1,2,kb+192); STG_A(1,3,kb+192); }
        BAR_LG0();
        MFMA16(1);
        __builtin_amdgcn_sched_barrier(0);
        __builtin_amdgcn_s_barrier();
        // ---- P5: buf1, acc pair 2; vm4 (drains t+2, keeps t+3.A)
        RD_B2(1, 2);
        BAR_LG0();
        MFMA16(2);
        __builtin_amdgcn_sched_barrier(0);
        if (more) { asm volatile("s_waitcnt vmcnt(4)" ::: "memory"); }
        __builtin_amdgcn_s_barrier();
    }
#undef RD_A
#undef RD_B2
#undef MFMA16
#undef BAR_LG0
#undef STG_A
#undef STG_B

    // ---- epilogue: acc[fm][fn][r] = C[m0+wm*64+fm*16+l15][n0+wn*96+fn*16+quad*4+r]
    const int mb = m0 + wm * 64;
    const int nb = n0 + wn * 96;

    if (n0 >= 2*DIM) {
        // V tiles: n0 in {1536,1728,1920,2112} (1536 = 8*192, clean split).
        // Per fn: 16-col block always within one head (16 | 64); 64-row span
        // within one batch (64 | 640). LDS transpose scratch -> vT[bh][d][tok].
        bf16* S = &As[0][0] + wave * 2048;
        unsigned short* Su = (unsigned short*)S;
        const int batch = mb / NN;
        const int tokb = mb % NN;
        const int dl = lane >> 2, cc = (lane & 3) * 16;
#pragma unroll
        for (int fn = 0; fn < 6; ++fn) {
            int cb = nb + fn*16;                  // 16-aligned col base
            int bh = batch * NH + ((cb - 2*DIM) >> 6);
            int dbase = cb & 63;
            float4 bv = *(const float4*)(bias + cb + quad*4);
            float bvr[4] = {bv.x, bv.y, bv.z, bv.w};
#pragma unroll
            for (int fm = 0; fm < 4; ++fm) {
#pragma unroll
                for (int r = 0; r < 4; ++r) {
                    float v = acc[fm][fn][r] + bvr[r];
                    Su[(quad*4 + r)*72 + fm*16 + l15] =
                        (unsigned short)(__float_as_uint(v) >> 16);
                }
            }
            // per-wave scratch: in-wave lgkmcnt ordering suffices
            uint4 r0 = *(const uint4*)(S + dl*72 + cc);
            uint4 r1 = *(const uint4*)(S + dl*72 + cc + 8);
            bf16* dst = vTo + ((size_t)bh * HD + dbase + dl) * NN + tokb + cc;
            *(uint4*)dst = r0;
            *(uint4*)(dst + 8) = r1;
        }
        return;
    }

#pragma unroll
    for (int fm = 0; fm < 4; ++fm) {
        int m = mb + fm*16 + l15;
        bf16* row = outb + (size_t)m * N;
#pragma unroll
        for (int fn = 0; fn < 6; ++fn) {
            int n = nb + fn*16 + quad*4;
            float4 bv = *(const float4*)(bias + n);
            float v0 = acc[fm][fn][0] + bv.x;
            float v1 = acc[fm][fn][1] + bv.y;
            float v2 = acc[fm][fn][2] + bv.z;
            float v3 = acc[fm][fn][3] + bv.w;
            if (n < DIM) { v0 *= QSCALE; v1 *= QSCALE; v2 *= QSCALE; v3 *= QSCALE; }
            *(uint2*)(row + n) = make_uint2(pack_rne(v0, v1), pack_rne(v2, v3));
        }
    }
}

// ---------------- proj GEMM: C = A @ B^T (128x128, round-1 structure) ----------------
template<int MODE>
__global__ __launch_bounds__(256) void gemm_bt(
    const bf16* __restrict__ A, const bf16* __restrict__ B, const float* __restrict__ bias,
    int M, int N, int K,
    bf16* __restrict__ outb, bf16* __restrict__ vTo, float* __restrict__ outf)
{
    __shared__ __align__(16) bf16 As[2][128*64];
    __shared__ __align__(16) bf16 Bs[2][128*64];

    const int t = threadIdx.x;
    const int lane = t & 63, wave = t >> 6;
    const int l15 = lane & 15, quad = lane >> 4;
    const int wm = (wave >> 1) * 64, wn = (wave & 1) * 64;

    constexpr int GX  = (MODE == 0) ? (QKVN/128) : (DIM/128);
    constexpr int NWG = GX * (MROWS/128);
    constexpr int CHUNK = NWG / 8;
    int lin = blockIdx.y * GX + blockIdx.x;
    lin = (lin & 7) * CHUNK + (lin >> 3);
    const int m0 = (lin / GX) * 128, n0 = (lin % GX) * 128;

    floatx4 acc[4][4];
    floatx4 zero = {0.f, 0.f, 0.f, 0.f};
    for (int i = 0; i < 4; ++i)
        for (int j = 0; j < 4; ++j)
            acc[i][j] = zero;

    const int trow = t >> 3;
    const int gc = ((t & 7) ^ (trow & 7)) << 3;
    const bf16* aA = A + (size_t)(m0 + trow) * K + gc;
    const bf16* aB = B + (size_t)(n0 + trow) * K + gc;
    const int lb = wave * 512;

    for (int s = 0; s < 4; ++s) {
        async_ld16(aA + (size_t)s*32*K, &As[0][s*2048 + lb]);
        async_ld16(aB + (size_t)s*32*K, &Bs[0][s*2048 + lb]);
    }

    const int sw = l15 & 7;
    const int nit = K >> 6;
    for (int kt = 0; kt < nit; ++kt) {
        const int cur = kt & 1;
        __syncthreads();
        if (kt + 1 < nit) {
            const bf16* pA = aA + (size_t)(kt+1)*64;
            const bf16* pB = aB + (size_t)(kt+1)*64;
            for (int s = 0; s < 4; ++s) {
                async_ld16(pA + (size_t)s*32*K, &As[cur^1][s*2048 + lb]);
                async_ld16(pB + (size_t)s*32*K, &Bs[cur^1][s*2048 + lb]);
            }
        }
        short8 af0[4], af1[4], bf0[4], bf1[4];
        for (int fm = 0; fm < 4; ++fm) {
            int base = (wm + fm*16 + l15) * 64 + ((quad ^ sw) << 3);
            af0[fm] = *(const short8*)(&As[cur][base]);
            af1[fm] = *(const short8*)(&As[cur][base ^ 32]);
        }
        for (int fn = 0; fn < 4; ++fn) {
            int base = (wn + fn*16 + l15) * 64 + ((quad ^ sw) << 3);
            bf0[fn] = *(const short8*)(&Bs[cur][base]);
            bf1[fn] = *(const short8*)(&Bs[cur][base ^ 32]);
        }
        for (int fm = 0; fm < 4; ++fm)
            for (int fn = 0; fn < 4; ++fn) {
                acc[fm][fn] = mfma16(bf0[fn], af0[fm], acc[fm][fn]);
                acc[fm][fn] = mfma16(bf1[fn], af1[fm], acc[fm][fn]);
            }
    }

    for (int fm = 0; fm < 4; ++fm) {
        int m = m0 + wm + fm*16 + l15;
        float* row = outf + (size_t)m * N;
        for (int fn = 0; fn < 4; ++fn) {
            int n = n0 + wn + fn*16 + quad*4;
            float4 bv = *(const float4*)(bias + n);
            float4 v;
            v.x = acc[fm][fn][0] + bv.x;
            v.y = acc[fm][fn][1] + bv.y;
            v.z = acc[fm][fn][2] + bv.z;
            v.w = acc[fm][fn][3] + bv.w;
            *(float4*)(row + n) = v;
        }
    }
}

// ---------------- fused attention v7: staged LDS, BK=64 ----------------
__global__ __launch_bounds__(256) void attn_kernel(
    const bf16* __restrict__ qkv, const bf16* __restrict__ vT,
    const float* __restrict__ w2, bf16* __restrict__ ao)
{
    int lin = blockIdx.y * BH + blockIdx.x;
    int j = lin >> 3;
    const int bh = (lin & 7) + 8 * (j / 10);
    const int qt = j % 10;
    const int b = bh / NH, h = bh - b * NH;
    const int t = threadIdx.x;
    const int wave = t >> 6, lane = t & 63;
    const int l15 = lane & 15, quad = lane >> 4;
    const int qrow0 = qt * 64 + wave * 16;

    float w0 = w2[0], w1 = w2[1];
    float wmx = fmaxf(w0, w1);
    float e0 = __expf(w0 - wmx), e1 = __expf(w1 - wmx);
    float ws0 = e0 / (e0 + e1);
    float ws1 = (1.0f - ws0) * LN2SQ;

    __shared__ __align__(16) bf16 Kb[2][64*64];
    __shared__ __align__(16) bf16 Vb[2][64*64];
    __shared__ __align__(16) bf16 Ps[4][16*72];
    __shared__ __align__(16) bf16 Pr[4][16*72];

    const bf16* kb = qkv + (size_t)(b*NN)*QKVN + DIM + h*HD;
    const bf16* vb = vT + (size_t)bh * HD * NN;

    const bf16* qr = qkv + (size_t)(b*NN + qrow0 + l15) * QKVN + h*HD;
    short8 aq0 = *(const short8*)(qr + quad*8);
    short8 aq1 = *(const short8*)(qr + 32 + quad*8);

    const int srow = t >> 3;
    const int gc   = ((lane & 7) ^ (lane >> 3)) << 3;
    const bf16* kst = kb + (size_t)srow * QKVN + gc;
    const bf16* vst = vb + (size_t)srow * NN + gc;
    const int lb0 = (wave * 64) * 8;
    const int lb1 = (256 + wave * 64) * 8;

    async_ld16(kst,                     &Kb[0][lb0]);
    async_ld16(kst + (size_t)32 * QKVN, &Kb[0][lb1]);
    async_ld16(vst,                     &Vb[0][lb0]);
    async_ld16(vst + (size_t)32 * NN,   &Vb[0][lb1]);

    floatx4 zero = {0.f, 0.f, 0.f, 0.f};
    floatx4 accS[4], accR[4];
    for (int i = 0; i < 4; ++i) { accS[i] = zero; accR[i] = zero; }
    float lsum = 0.f;

    const int sw = l15 & 7;
    const int fbase = l15 * 64 + ((quad ^ sw) << 3);

    unsigned* PsW = (unsigned*)&Ps[wave][0];
    unsigned* PrW = (unsigned*)&Pr[wave][0];
    const int wb = l15*36 + quad*2;
    const bf16* PsR = &Ps[wave][l15*72 + quad*8];
    const bf16* PrR = &Pr[wave][l15*72 + quad*8];

#pragma unroll 2
    for (int kt = 0; kt < 10; ++kt) {
        const int cur = kt & 1;
        __syncthreads();
        if (kt + 1 < 10) {
            kst += (size_t)64 * QKVN;
            vst += 64;
            async_ld16(kst,                     &Kb[cur^1][lb0]);
            async_ld16(kst + (size_t)32 * QKVN, &Kb[cur^1][lb1]);
            async_ld16(vst,                     &Vb[cur^1][lb0]);
            async_ld16(vst + (size_t)32 * NN,   &Vb[cur^1][lb1]);
        }

        const bf16* Kc = &Kb[cur][0];
        const bf16* Vc = &Vb[cur][0];

        floatx4 s[4];
        for (int I = 0; I < 4; ++I) {
            short8 aklo = *(const short8*)(Kc + fbase + I*1024);
            short8 akhi = *(const short8*)(Kc + ((fbase + I*1024) ^ 32));
            s[I] = zero;
            s[I] = mfma16(aklo, aq0, s[I]);
            s[I] = mfma16(akhi, aq1, s[I]);
        }

        short8 bvlo[4], bvhi[4];
        for (int dt = 0; dt < 4; ++dt) {
            bvlo[dt] = *(const short8*)(Vc + fbase + dt*1024);
            bvhi[dt] = *(const short8*)(Vc + ((fbase + dt*1024) ^ 32));
        }

        for (int I = 0; I < 4; ++I) {
            float ex[4], rq[4];
            for (int r = 0; r < 4; ++r) {
                ex[r] = fexp2(s[I][r]);
                float m = fmaxf(s[I][r], 0.f);
                rq[r] = m * m;
                lsum += ex[r];
            }
            *(uint2*)(PsW + wb + I*8) = make_uint2(pack_trunc(ex[0],ex[1]), pack_trunc(ex[2],ex[3]));
            *(uint2*)(PrW + wb + I*8) = make_uint2(pack_trunc(rq[0],rq[1]), pack_trunc(rq[2],rq[3]));
        }

        short8 paSlo = *(const short8*)PsR;
        short8 paShi = *(const short8*)(PsR + 32);
        short8 paRlo = *(const short8*)PrR;
        short8 paRhi = *(const short8*)(PrR + 32);

        for (int dt = 0; dt < 4; ++dt) {
            accS[dt] = mfma16(paSlo, bvlo[dt], accS[dt]);
            accS[dt] = mfma16(paShi, bvhi[dt], accS[dt]);
            accR[dt] = mfma16(paRlo, bvlo[dt], accR[dt]);
            accR[dt] = mfma16(paRhi, bvhi[dt], accR[dt]);
        }
    }

    lsum += __shfl_xor(lsum, 16);
    lsum += __shfl_xor(lsum, 32);
    float invq[4];
    for (int r = 0; r < 4; ++r)
        invq[r] = 1.0f / __shfl(lsum, quad*4 + r);

    for (int dt = 0; dt < 4; ++dt) {
        for (int r = 0; r < 4; ++r) {
            float v = ws0 * accS[dt][r] * invq[r] + ws1 * accR[dt][r];
            int tok = qrow0 + quad*4 + r;
            ao[((size_t)(b * NN + tok)) * DIM + h * HD + dt*16 + l15] = __float2bfloat16(v);
        }
    }
}

// ---------------- launch ----------------

extern "C" void kernel_launch(void* const* d_in, const int* in_sizes, int n_in,
                              void* d_out, int out_size, void* d_ws, size_t ws_size,
                              hipStream_t stream) {
    const float* x      = (const float*)d_in[0];
    const float* qkv_w  = (const float*)d_in[1];
    const float* qkv_b  = (const float*)d_in[2];
    const float* proj_w = (const float*)d_in[3];
    const float* proj_b = (const float*)d_in[4];
    const float* w2     = (const float*)d_in[5];
    float* out = (float*)d_out;

    bf16* xb   = (bf16*)d_ws;                       // 10240*768   (reused as ao later)
    bf16* qwT  = xb   + (size_t)MROWS * DIM;        // 2304*768
    bf16* pwT  = qwT  + (size_t)QKVN * DIM;         // 768*768
    bf16* qkvb = pwT  + (size_t)DIM * DIM;          // 10240*2304 (V cols unused)
    bf16* vT   = qkvb + (size_t)MROWS * QKVN;       // 192*64*640
    bf16* ao   = xb;                                 // alias: xb dead after qkv gemm

    prep_all<<<CVT_BLK + TRQ_BLK + TRP_BLK, 256, 0, stream>>>(
        x, qkv_w, proj_w, xb, qwT, pwT);

    gemm_qkv<<<dim3((QKVN/192) * (MROWS/256)), 512, 0, stream>>>(
        xb, qwT, qkv_b, qkvb, vT);

    attn_kernel<<<dim3(BH, NN / 64), 256, 0, stream>>>(qkvb, vT, w2, ao);

    gemm_bt<1><<<dim3(DIM / 128, MROWS / 128), 256, 0, stream>>>(
        ao, pwT, proj_b, MROWS, DIM, DIM, nullptr, nullptr, out);
}